// Round 2
// baseline (157.804 us; speedup 1.0000x reference)
//
#include <hip/hip_runtime.h>

// Fused 2-level inverse Haar DWT (UnPatcher, PATCH_SIZE=4), float4-vectorized.
// Input  x:   [8, 256, 96, 96]  fp32
// Output out: [8, 16, 384, 384] fp32
//
// Each thread: one (b, g, p, qv) with qv = q/4. Reads 16 float4 (the 16
// channels at 4 consecutive q), applies the 2-level +/-1 butterfly per
// component (per-level scale 2*S*S == 1), writes a 4x16 output tile as
// 16 float4 stores.

#define B_  8
#define CIN 256
#define G_  16
#define H_  96
#define W_  96
#define OW  384
#define QV  (W_ / 4)

#define COMP(f, j) ((j) == 0 ? (f).x : (j) == 1 ? (f).y : (j) == 2 ? (f).z : (f).w)

__global__ __launch_bounds__(256) void idwt2_fused_v4(const float* __restrict__ x,
                                                      float* __restrict__ out) {
    const int N = B_ * G_ * H_ * QV;  // 294912
    int idx = blockIdx.x * blockDim.x + threadIdx.x;
    if (idx >= N) return;

    int qv = idx % QV;
    int t1 = idx / QV;
    int p  = t1 % H_;
    int t2 = t1 / H_;
    int g  = t2 % G_;
    int b  = t2 / G_;

    const size_t plane = (size_t)H_ * W_;  // 9216
    const float* xin = x + (size_t)b * CIN * plane + (size_t)p * W_ + 4 * (size_t)qv;

    // v[k][m] = x[b, g + 16k + 64m, p, 4qv .. 4qv+3]
    float4 v[4][4];
#pragma unroll
    for (int k = 0; k < 4; ++k) {
#pragma unroll
        for (int m = 0; m < 4; ++m) {
            v[k][m] = *reinterpret_cast<const float4*>(xin + (size_t)(g + 16 * k + 64 * m) * plane);
        }
    }

    float* obase = out + ((size_t)(b * G_ + g) * OW + 4 * (size_t)p) * OW + 16 * (size_t)qv;

#pragma unroll
    for (int j = 0; j < 4; ++j) {
        // Level 1 (channel stride 64): t[k][2*dh+dw]
        float t[4][4];
#pragma unroll
        for (int k = 0; k < 4; ++k) {
            float a = COMP(v[k][0], j);
            float bb = COMP(v[k][1], j);
            float c = COMP(v[k][2], j);
            float d = COMP(v[k][3], j);
            float u0 = a + bb, u1 = a - bb;
            float u2 = c + d,  u3 = c - d;
            t[k][0] = u0 + u2;  // dh=0,dw=0
            t[k][1] = u0 - u2;  // dh=0,dw=1
            t[k][2] = u1 + u3;  // dh=1,dw=0
            t[k][3] = u1 - u3;  // dh=1,dw=1
        }

        // Level 2 (channel stride 16): w[r] = output row r, cols 4j..4j+3 of this tile
        float4 w[4];
#pragma unroll
        for (int dh = 0; dh < 2; ++dh) {
            // dw = 0 -> components .x (ew=0), .y (ew=1)
            {
                int i = 2 * dh + 0;
                float a0 = t[0][i] + t[1][i];
                float a1 = t[0][i] - t[1][i];
                float a2 = t[2][i] + t[3][i];
                float a3 = t[2][i] - t[3][i];
                w[2 * dh + 0].x = a0 + a2;
                w[2 * dh + 0].y = a0 - a2;
                w[2 * dh + 1].x = a1 + a3;
                w[2 * dh + 1].y = a1 - a3;
            }
            // dw = 1 -> components .z (ew=0), .w (ew=1)
            {
                int i = 2 * dh + 1;
                float a0 = t[0][i] + t[1][i];
                float a1 = t[0][i] - t[1][i];
                float a2 = t[2][i] + t[3][i];
                float a3 = t[2][i] - t[3][i];
                w[2 * dh + 0].z = a0 + a2;
                w[2 * dh + 0].w = a0 - a2;
                w[2 * dh + 1].z = a1 + a3;
                w[2 * dh + 1].w = a1 - a3;
            }
        }

#pragma unroll
        for (int r = 0; r < 4; ++r) {
            *reinterpret_cast<float4*>(obase + (size_t)r * OW + 4 * j) = w[r];
        }
    }
}

extern "C" void kernel_launch(void* const* d_in, const int* in_sizes, int n_in,
                              void* d_out, int out_size, void* d_ws, size_t ws_size,
                              hipStream_t stream) {
    const float* x = (const float*)d_in[0];
    float* out = (float*)d_out;
    const int N = B_ * G_ * H_ * QV;          // 294912
    const int block = 256;
    const int grid = (N + block - 1) / block; // 1152
    idwt2_fused_v4<<<grid, block, 0, stream>>>(x, out);
}

// Round 3
// 129.502 us; speedup vs baseline: 1.2185x; 1.2185x over previous
//
#include <hip/hip_runtime.h>

// Fused 2-level inverse Haar DWT (UnPatcher, PATCH_SIZE=4), LDS-staged.
// Input  x:   [8, 256, 96, 96]  fp32
// Output out: [8, 16, 384, 384] fp32
//
// Block = 384 threads, tile = (b, g, 4 input rows, 96 q).
//  Phase 1: 1536 float4 chunks (16 ch x 4 rows x 24 q-chunks) loaded flat,
//           4 global_load_dwordx4 per thread -> LDS.
//  Phase 2: thread (r, q) reads 16 scalars from LDS (2 lanes/bank, free),
//           2-level +/-1 butterfly (per-level scale 2*S*S == 1), writes a
//           4x4 output tile as 4 lane-contiguous global_store_dwordx4
//           (1 KB contiguous per wave per store).

#define B_   8
#define CIN  256
#define G_   16
#define H_   96
#define W_   96
#define OW   384
#define ROWS 4                     // input rows per block
#define NT   (ROWS * W_)           // 384 threads
#define NCHUNK (16 * ROWS * (W_ / 4))  // 1536 float4 chunks per tile

__global__ __launch_bounds__(NT) void idwt2_lds(const float* __restrict__ x,
                                                float* __restrict__ out) {
    __shared__ float lds[16 * ROWS * W_];  // 24 KB: [ch_idx][row][q]

    const int tid = threadIdx.x;
    // blockIdx.x = ((b*G_ + g) * (H_/ROWS)) + pblk
    int bid  = blockIdx.x;
    int pblk = bid % (H_ / ROWS);
    int bg   = bid / (H_ / ROWS);      // b*G_ + g
    int g    = bg % G_;
    int b    = bg / G_;
    int p0   = pblk * ROWS;

    const size_t plane = (size_t)H_ * W_;  // 9216
    const float* xb = x + (size_t)b * CIN * plane;

    // ---- Phase 1: global -> LDS ----
#pragma unroll
    for (int it = 0; it < NCHUNK / NT; ++it) {
        int i      = tid + it * NT;       // 0..1535
        int ch_idx = i / (ROWS * (W_ / 4));   // /96
        int rem    = i % (ROWS * (W_ / 4));
        int row    = rem / (W_ / 4);          // /24
        int cq     = rem % (W_ / 4);
        int k = ch_idx & 3;
        int m = ch_idx >> 2;
        int channel = g + 16 * k + 64 * m;
        float4 f = *reinterpret_cast<const float4*>(
            xb + (size_t)channel * plane + (size_t)(p0 + row) * W_ + 4 * cq);
        *reinterpret_cast<float4*>(&lds[(ch_idx * ROWS + row) * W_ + 4 * cq]) = f;
    }
    __syncthreads();

    // ---- Phase 2: butterfly + store ----
    int r = tid / W_;   // 0..3
    int q = tid % W_;   // 0..95

    float v[4][4];  // v[k][m]
#pragma unroll
    for (int k = 0; k < 4; ++k) {
#pragma unroll
        for (int m = 0; m < 4; ++m) {
            v[k][m] = lds[((k + 4 * m) * ROWS + r) * W_ + q];
        }
    }

    // Level 1 (inner, channel stride 64): t[k][2*dh+dw]
    float t[4][4];
#pragma unroll
    for (int k = 0; k < 4; ++k) {
        float u0 = v[k][0] + v[k][1];
        float u1 = v[k][0] - v[k][1];
        float u2 = v[k][2] + v[k][3];
        float u3 = v[k][2] - v[k][3];
        t[k][0] = u0 + u2;
        t[k][1] = u0 - u2;
        t[k][2] = u1 + u3;
        t[k][3] = u1 - u3;
    }

    // Level 2 (outer, channel stride 16)
    float rowv[4][4];
#pragma unroll
    for (int dh = 0; dh < 2; ++dh) {
#pragma unroll
        for (int dw = 0; dw < 2; ++dw) {
            int i = 2 * dh + dw;
            float a0 = t[0][i] + t[1][i];
            float a1 = t[0][i] - t[1][i];
            float a2 = t[2][i] + t[3][i];
            float a3 = t[2][i] - t[3][i];
            rowv[2 * dh + 0][2 * dw + 0] = a0 + a2;
            rowv[2 * dh + 0][2 * dw + 1] = a0 - a2;
            rowv[2 * dh + 1][2 * dw + 0] = a1 + a3;
            rowv[2 * dh + 1][2 * dw + 1] = a1 - a3;
        }
    }

    float* obase = out + ((size_t)(b * G_ + g) * OW + 4 * (size_t)(p0 + r)) * OW + 4 * (size_t)q;
#pragma unroll
    for (int rr = 0; rr < 4; ++rr) {
        float4 f4 = make_float4(rowv[rr][0], rowv[rr][1], rowv[rr][2], rowv[rr][3]);
        *reinterpret_cast<float4*>(obase + (size_t)rr * OW) = f4;
    }
}

extern "C" void kernel_launch(void* const* d_in, const int* in_sizes, int n_in,
                              void* d_out, int out_size, void* d_ws, size_t ws_size,
                              hipStream_t stream) {
    const float* x = (const float*)d_in[0];
    float* out = (float*)d_out;
    const int grid = B_ * G_ * (H_ / ROWS);  // 3072
    idwt2_lds<<<grid, NT, 0, stream>>>(x, out);
}